// Round 1
// baseline (1420.490 us; speedup 1.0000x reference)
//
#include <hip/hip_runtime.h>
#include <math.h>

#define NPTS 9216          // 96*96
#define CDIM 256
#define WW 96
#define W2 192
#define MACT (192*192)
#define NCHUNK 8
#define CHUNK_COLS (NPTS / NCHUNK)   // 1152
#define BM 64
#define BN 64
#define KB 64
#define ROWBLK (NPTS / BM)           // 144
#define NTILES (CHUNK_COLS / BN)     // 18

__device__ __forceinline__ void feed(float v, int i, float& v0, int& i0, float& v1, int& i1) {
    if (v > v0) { v1 = v0; i1 = i0; v0 = v; i0 = i; }
    else if (v > v1) { v1 = v; i1 = i; }
}

// normalize (C,N) map per column p (unit L2 over channels), same layout out
__global__ void norm_map_k(const float* __restrict__ src, float* __restrict__ dst) {
    int p = blockIdx.x * blockDim.x + threadIdx.x;
    if (p >= NPTS) return;
    float s = 0.f;
    for (int c = 0; c < CDIM; ++c) { float v = src[(size_t)c * NPTS + p]; s += v * v; }
    float inv = 1.0f / sqrtf(s);
    for (int c = 0; c < CDIM; ++c) dst[(size_t)c * NPTS + p] = src[(size_t)c * NPTS + p] * inv;
}

// sim = A^T B with A,B stored (C,N). Block (bx,cc): rows [bx*64,+64), cols chunk cc (1152 cols).
// Emits per-(row,chunk) top2 partials and per-(col,rowblock) top2 partials.
__global__ __launch_bounds__(256) void sim_top2_k(const float* __restrict__ A, const float* __restrict__ B,
                                                  float4* __restrict__ prow, float4* __restrict__ pcol) {
    __shared__ float As[KB][BM];
    __shared__ float Bs[KB][BN];
    __shared__ float4 red[16][65];
    int bx = blockIdx.x, cc = blockIdx.y;
    int p0 = bx * BM;
    int tid = threadIdx.x;
    int tx = tid & 15, ty = tid >> 4;

    float rv0[4], rv1[4];
    int ri0[4], ri1[4];
    #pragma unroll
    for (int r = 0; r < 4; ++r) { rv0[r] = rv1[r] = -3.0e38f; ri0[r] = ri1[r] = 0; }

    for (int t = 0; t < NTILES; ++t) {
        int q0 = cc * CHUNK_COLS + t * BN;
        float acc[4][4] = {{0.f}};
        for (int kc = 0; kc < CDIM / KB; ++kc) {
            int k0 = kc * KB;
            __syncthreads();
            #pragma unroll
            for (int r = 0; r < 4; ++r) {
                int kk = r * 16 + ty;
                *(float4*)&As[kk][tx * 4] = *(const float4*)&A[(size_t)(k0 + kk) * NPTS + p0 + tx * 4];
                *(float4*)&Bs[kk][tx * 4] = *(const float4*)&B[(size_t)(k0 + kk) * NPTS + q0 + tx * 4];
            }
            __syncthreads();
            #pragma unroll 8
            for (int kk = 0; kk < KB; ++kk) {
                float4 a = *(const float4*)&As[kk][ty * 4];
                float4 b = *(const float4*)&Bs[kk][tx * 4];
                acc[0][0] += a.x * b.x; acc[0][1] += a.x * b.y; acc[0][2] += a.x * b.z; acc[0][3] += a.x * b.w;
                acc[1][0] += a.y * b.x; acc[1][1] += a.y * b.y; acc[1][2] += a.y * b.z; acc[1][3] += a.y * b.w;
                acc[2][0] += a.z * b.x; acc[2][1] += a.z * b.y; acc[2][2] += a.z * b.z; acc[2][3] += a.z * b.w;
                acc[3][0] += a.w * b.x; acc[3][1] += a.w * b.y; acc[3][2] += a.w * b.z; acc[3][3] += a.w * b.w;
            }
        }
        // update running row top2 (cols ascending: tiles ascending, j ascending)
        #pragma unroll
        for (int r = 0; r < 4; ++r)
            #pragma unroll
            for (int j = 0; j < 4; ++j)
                feed(acc[r][j], q0 + tx * 4 + j, rv0[r], ri0[r], rv1[r], ri1[r]);
        // column partial top2 over this block's 64 rows
        #pragma unroll
        for (int j = 0; j < 4; ++j) {
            float cv0 = -3.0e38f, cv1 = -3.0e38f; int ci0 = 0, ci1 = 0;
            #pragma unroll
            for (int r = 0; r < 4; ++r) feed(acc[r][j], p0 + ty * 4 + r, cv0, ci0, cv1, ci1);
            red[ty][tx * 4 + j] = make_float4(cv0, cv1, __int_as_float(ci0), __int_as_float(ci1));
        }
        __syncthreads();
        if (tid < BN) {
            float v0 = -3.0e38f, v1 = -3.0e38f; int i0 = 0, i1 = 0;
            for (int g = 0; g < 16; ++g) {   // g=ty ascending => rows ascending
                float4 s = red[g][tid];
                feed(s.x, __float_as_int(s.z), v0, i0, v1, i1);
                feed(s.y, __float_as_int(s.w), v0, i0, v1, i1);
            }
            pcol[(size_t)bx * NPTS + q0 + tid] = make_float4(v0, v1, __int_as_float(i0), __int_as_float(i1));
        }
        __syncthreads();
    }
    // block-level row top2: reduce across tx groups
    #pragma unroll
    for (int r = 0; r < 4; ++r)
        red[tx][ty * 4 + r] = make_float4(rv0[r], rv1[r], __int_as_float(ri0[r]), __int_as_float(ri1[r]));
    __syncthreads();
    if (tid < BM) {
        float v0 = -3.0e38f, v1 = -3.0e38f; int i0 = 0, i1 = 0;
        for (int g = 0; g < 16; ++g) {       // g=tx ascending => cols ascending
            float4 s = red[g][tid];
            feed(s.x, __float_as_int(s.z), v0, i0, v1, i1);
            feed(s.y, __float_as_int(s.w), v0, i0, v1, i1);
        }
        prow[(size_t)cc * NPTS + p0 + tid] = make_float4(v0, v1, __int_as_float(i0), __int_as_float(i1));
    }
}

__global__ void merge_rows_k(const float4* __restrict__ prow, int* __restrict__ nn12,
                             float* __restrict__ msim, float* __restrict__ r12) {
    int p = blockIdx.x * blockDim.x + threadIdx.x;
    if (p >= NPTS) return;
    float v0 = -3.0e38f, v1 = -3.0e38f; int i0 = 0, i1 = 0;
    for (int c = 0; c < NCHUNK; ++c) {
        float4 s = prow[(size_t)c * NPTS + p];
        feed(s.x, __float_as_int(s.z), v0, i0, v1, i1);
        feed(s.y, __float_as_int(s.w), v0, i0, v1, i1);
    }
    nn12[p] = i0; msim[p] = v0;
    r12[p] = (2.0f - 2.0f * v0) / ((2.0f - 2.0f * v1) + 1e-8f);
}

__global__ void merge_cols_k(const float4* __restrict__ pcol, int* __restrict__ nn21, float* __restrict__ r21) {
    int q = blockIdx.x * blockDim.x + threadIdx.x;
    if (q >= NPTS) return;
    float v0 = -3.0e38f, v1 = -3.0e38f; int i0 = 0, i1 = 0;
    for (int k = 0; k < ROWBLK; ++k) {
        float4 s = pcol[(size_t)k * NPTS + q];
        feed(s.x, __float_as_int(s.z), v0, i0, v1, i1);
        feed(s.y, __float_as_int(s.w), v0, i0, v1, i1);
    }
    nn21[q] = i0;
    r21[q] = (2.0f - 2.0f * v0) / ((2.0f - 2.0f * v1) + 1e-8f);
}

__global__ void valid_k(const int* __restrict__ nn12, const float* __restrict__ r12,
                        const int* __restrict__ nn21, const float* __restrict__ r21,
                        int* __restrict__ validv) {
    int p = blockIdx.x * blockDim.x + threadIdx.x;
    if (p >= NPTS) return;
    int nn = nn12[p];
    bool mnn = (nn21[nn] == p) && (r12[p] <= 0.95f) && (r21[nn] <= 0.95f);
    int xA = p % WW, yA = p / WW, xB = nn % WW, yB = nn / WW;
    bool disc = (xA == 0) | (xA == WW - 1) | (yA == 0) | (yA == WW - 1) |
                (xB == 0) | (xB == WW - 1) | (yB == 0) | (yB == WW - 1);
    validv[p] = (mnn && !disc) ? 1 : 0;
}

// one block (256 threads = 256 channels) per point
__global__ __launch_bounds__(256) void refine_k(const float* __restrict__ actA, const float* __restrict__ actB,
                                                const int* __restrict__ nn12, const float* __restrict__ msim,
                                                const int* __restrict__ validv, float* __restrict__ out) {
    int n = blockIdx.x;
    int c = threadIdx.x;
    int val = validv[n];
    int nn = nn12[n];
    int xA = n % WW, yA = n / WW;
    int xB = nn % WW, yB = nn / WW;
    int pAx = val ? 2 * xA : 2, pAy = val ? 2 * yA : 2;
    int pBx = val ? 2 * xB : 2, pBy = val ? 2 * yB : 2;
    const int nxv[4] = {0, 0, 1, 1};
    const int nyv[4] = {0, 1, 0, 1};
    float a[4], b[4];
    #pragma unroll
    for (int i = 0; i < 4; ++i) {
        a[i] = actA[(size_t)c * MACT + (pAy + nyv[i]) * W2 + pAx + nxv[i]];
        b[i] = actB[(size_t)c * MACT + (pBy + nyv[i]) * W2 + pBx + nxv[i]];
    }
    float vals[24];
    #pragma unroll
    for (int i = 0; i < 4; ++i) vals[i] = a[i] * a[i];
    #pragma unroll
    for (int j = 0; j < 4; ++j) vals[4 + j] = b[j] * b[j];
    #pragma unroll
    for (int i = 0; i < 4; ++i)
        #pragma unroll
        for (int j = 0; j < 4; ++j) vals[8 + i * 4 + j] = a[i] * b[j];
    #pragma unroll
    for (int v = 0; v < 24; ++v) {
        float x = vals[v];
        #pragma unroll
        for (int m = 1; m < 64; m <<= 1) x += __shfl_xor(x, m);
        vals[v] = x;
    }
    __shared__ float part[24][4];
    __shared__ float fin[24];
    int wave = c >> 6, lane = c & 63;
    if (lane == 0) {
        #pragma unroll
        for (int v = 0; v < 24; ++v) part[v][wave] = vals[v];
    }
    __syncthreads();
    if (c < 24) fin[c] = part[c][0] + part[c][1] + part[c][2] + part[c][3];
    __syncthreads();
    if (c == 0) {
        float rsA[4], rsB[4], sc[4][4];
        #pragma unroll
        for (int i = 0; i < 4; ++i) rsA[i] = 1.0f / sqrtf(fin[i]);
        #pragma unroll
        for (int j = 0; j < 4; ++j) rsB[j] = 1.0f / sqrtf(fin[4 + j]);
        #pragma unroll
        for (int i = 0; i < 4; ++i)
            #pragma unroll
            for (int j = 0; j < 4; ++j) sc[i][j] = fin[8 + i * 4 + j] * rsA[i] * rsB[j];

        float ratA[4], scoreA[4]; int mAB[4];
        #pragma unroll
        for (int i = 0; i < 4; ++i) {
            float v0 = -3.0e38f, v1 = -3.0e38f; int i0 = 0, i1 = 0;
            #pragma unroll
            for (int j = 0; j < 4; ++j) feed(sc[i][j], j, v0, i0, v1, i1);
            float d0 = 2.0f - 2.0f * v0, d1 = 2.0f - 2.0f * v1;
            ratA[i] = d0 / (d1 + 1e-8f);
            scoreA[i] = d0; mAB[i] = i0;
        }
        float ratB[4]; int mBA[4];
        #pragma unroll
        for (int j = 0; j < 4; ++j) {
            float v0 = -3.0e38f, v1 = -3.0e38f; int i0 = 0, i1 = 0;
            #pragma unroll
            for (int i = 0; i < 4; ++i) feed(sc[i][j], i, v0, i0, v1, i1);
            float d0 = 2.0f - 2.0f * v0, d1 = 2.0f - 2.0f * v1;
            ratB[j] = d0 / (d1 + 1e-8f);
            mBA[j] = i0;
        }
        bool rm[4];
        #pragma unroll
        for (int i = 0; i < 4; ++i) {
            bool cyc = (mBA[mAB[i]] == i);
            rm[i] = (fmaxf(ratA[i], ratB[i]) < 0.9f) && cyc;
        }
        float sm[4];
        #pragma unroll
        for (int i = 0; i < 4; ++i) sm[i] = rm[i] ? scoreA[i] : 5.0f;
        {   // disc: top2 (largest, ties -> lowest index) of sm, clear those rmask entries
            float v0 = -3.0e38f, v1 = -3.0e38f; int i0 = 0, i1 = 0;
            #pragma unroll
            for (int i = 0; i < 4; ++i) feed(sm[i], i, v0, i0, v1, i1);
            rm[i0] = false; rm[i1] = false;
        }
        out[n * 5 + 0] = msim[n];
        #pragma unroll
        for (int i = 0; i < 4; ++i) out[n * 5 + 1 + i] = sm[i];
        size_t b2 = (size_t)NPTS * 5;
        #pragma unroll
        for (int i = 0; i < 4; ++i) out[b2 + (size_t)n * 4 + i] = (float)(pAx + nxv[i]);
        #pragma unroll
        for (int i = 0; i < 4; ++i) out[b2 + (size_t)NPTS * 4 + (size_t)n * 4 + i] = (float)(pAy + nyv[i]);
        size_t b3 = b2 + (size_t)NPTS * 8;
        #pragma unroll
        for (int i = 0; i < 4; ++i) out[b3 + (size_t)n * 4 + i] = (float)(pBx + nxv[mAB[i]]);
        #pragma unroll
        for (int i = 0; i < 4; ++i) out[b3 + (size_t)NPTS * 4 + (size_t)n * 4 + i] = (float)(pBy + nyv[mAB[i]]);
        size_t b4 = b3 + (size_t)NPTS * 8;
        #pragma unroll
        for (int i = 0; i < 4; ++i) out[b4 + (size_t)n * 4 + i] = (rm[i] && val) ? 1.0f : 0.0f;
    }
}

extern "C" void kernel_launch(void* const* d_in, const int* in_sizes, int n_in,
                              void* d_out, int out_size, void* d_ws, size_t ws_size,
                              hipStream_t stream) {
    const float* mapA = (const float*)d_in[0];
    const float* mapB = (const float*)d_in[1];
    const float* actA = (const float*)d_in[2];
    const float* actB = (const float*)d_in[3];
    float* out = (float*)d_out;

    float* d1n = (float*)d_ws;
    float* d2n = d1n + (size_t)CDIM * NPTS;
    float4* prow = (float4*)(d2n + (size_t)CDIM * NPTS);
    float4* pcol = prow + (size_t)NCHUNK * NPTS;
    int* nn12 = (int*)(pcol + (size_t)ROWBLK * NPTS);
    float* msim = (float*)(nn12 + NPTS);
    float* r12 = msim + NPTS;
    int* nn21 = (int*)(r12 + NPTS);
    float* r21 = (float*)(nn21 + NPTS);
    int* validv = (int*)(r21 + NPTS);

    norm_map_k<<<NPTS / 256, 256, 0, stream>>>(mapA, d1n);
    norm_map_k<<<NPTS / 256, 256, 0, stream>>>(mapB, d2n);
    dim3 g2(ROWBLK, NCHUNK);
    sim_top2_k<<<g2, 256, 0, stream>>>(d1n, d2n, prow, pcol);
    merge_rows_k<<<NPTS / 256, 256, 0, stream>>>(prow, nn12, msim, r12);
    merge_cols_k<<<NPTS / 256, 256, 0, stream>>>(pcol, nn21, r21);
    valid_k<<<NPTS / 256, 256, 0, stream>>>(nn12, r12, nn21, r21, validv);
    refine_k<<<NPTS, 256, 0, stream>>>(actA, actB, nn12, msim, validv, out);
}